// Round 16
// baseline (204.578 us; speedup 1.0000x reference)
//
#include <hip/hip_runtime.h>
#include <hip/hip_bf16.h>

typedef __hip_bfloat16 bf16;
typedef __attribute__((ext_vector_type(8))) short short8;   // 8 bf16 = 4 VGPRs (x32 A/B frag)
typedef __attribute__((ext_vector_type(4))) short short4v;  // 4 bf16 = 2 VGPRs (x16 A/B frag)
typedef __attribute__((ext_vector_type(4))) float f32x4;    // MFMA C/D frag

#define MFMA16(a, b, c) __builtin_amdgcn_mfma_f32_16x16x32_bf16((a), (b), (c), 0, 0, 0)

// 16x16x16 bf16 MFMA: builtin name varies across ROCm; asm fallback.
#if __has_builtin(__builtin_amdgcn_mfma_f32_16x16x16bf16_1k)
#define MFMA_PV(a, b, c) __builtin_amdgcn_mfma_f32_16x16x16bf16_1k((a), (b), (c), 0, 0, 0)
#elif __has_builtin(__builtin_amdgcn_mfma_f32_16x16x16_bf16)
#define MFMA_PV(a, b, c) __builtin_amdgcn_mfma_f32_16x16x16_bf16((a), (b), (c), 0, 0, 0)
#else
static __device__ __forceinline__ f32x4 mfma_pv_asm(short4v a, short4v b, f32x4 c) {
    f32x4 d;
    asm volatile("v_mfma_f32_16x16x16_bf16 %0, %1, %2, %3"
                 : "=&v"(d) : "v"(a), "v"(b), "v"(c));
    return d;
}
#define MFMA_PV(a, b, c) mfma_pv_asm((a), (b), (c))
#endif

// async global->LDS, 16B per lane; LDS dest must be wave-uniform base + lane*16
static __device__ __forceinline__ void gload_lds16(const bf16* g, bf16* l) {
    __builtin_amdgcn_global_load_lds((const __attribute__((address_space(1))) void*)g,
                                     (__attribute__((address_space(3))) void*)l, 16, 0, 0);
}

// ---------------------------------------------------------------------------
// Kernel 1 (merged): preprocessing — blocks 0..1023 transpose+cast weights,
// blocks 1024..5119 cast x (fp32->bf16). One launch (round-11 win, ~2.5 us).
// ---------------------------------------------------------------------------
__global__ __launch_bounds__(256) void prep_kernel(
    const float* __restrict__ x, bf16* __restrict__ Xb,
    const float* __restrict__ wq, const float* __restrict__ wk,
    const float* __restrict__ wv, const float* __restrict__ wo,
    bf16* __restrict__ WqkvT, bf16* __restrict__ WoT) {
    __shared__ bf16 tile[64][65];
    int bidx = blockIdx.x;
    if (bidx >= 1024) {
        // cast path
        int i = ((bidx - 1024) * 256 + threadIdx.x) * 4;
        float4 v = *(const float4*)(x + i);
        union { bf16 h4[4]; uint2 u; } p;
        p.h4[0] = __float2bfloat16(v.x);
        p.h4[1] = __float2bfloat16(v.y);
        p.h4[2] = __float2bfloat16(v.z);
        p.h4[3] = __float2bfloat16(v.w);
        *(uint2*)(Xb + i) = p.u;
        return;
    }
    // transpose path
    int mat = bidx >> 8;
    int t   = bidx & 255;
    int tn  = t >> 4, tk = t & 15;
    const float* src = (mat == 0) ? wq : (mat == 1) ? wk : (mat == 2) ? wv : wo;
    bf16* dst = (mat < 3) ? (WqkvT + (size_t)mat * 1024 * 1024) : WoT;
    int tx = threadIdx.x & 63, ty = threadIdx.x >> 6;
    int k0 = tk * 64, n0 = tn * 64;
#pragma unroll
    for (int p = 0; p < 16; ++p) {
        int r = p * 4 + ty;
        tile[r][tx] = __float2bfloat16(src[(size_t)(k0 + r) * 1024 + n0 + tx]);
    }
    __syncthreads();
#pragma unroll
    for (int p = 0; p < 16; ++p) {
        int r = p * 4 + ty;
        dst[(size_t)(n0 + r) * 1024 + k0 + tx] = tile[tx][r];
    }
}

// ---------------------------------------------------------------------------
// Kernel 3: GEMM1  QKV = Xb @ WqkvT^T.  Round-15: BK 32->64 (halves the
// per-K-step vmcnt(0)+barrier drains: 16 steps x 2 barriers vs 32 x 2; 32
// MFMA/wave between barriers vs 16) + T2 XOR swizzle for the now-128B-stride
// frag reads (chunk ^= row&7; pre-swizzled GLOBAL source + linear gload_lds
// dest + swizzled ds_read — both-sides involution per rule #21). LDS 32KB
// (occupancy unchanged; m132's BK=128 regression was the 64KB cliff).
// Q pre-scale by s1 in epilogue (round-14 win) retained.
// ---------------------------------------------------------------------------
__global__ __launch_bounds__(256) void gemm_qkv_kernel(
    const bf16* __restrict__ A, const bf16* __restrict__ Bt,
    bf16* __restrict__ QK, bf16* __restrict__ Vt) {
    const int K = 1024;
    int bm = blockIdx.x, bn = blockIdx.y;
    __shared__ bf16 As[128 * 64];
    __shared__ bf16 Bs[128 * 64];
    int tid = threadIdx.x;
    int lane = tid & 63, w = tid >> 6;
    int wm = (w >> 1) * 64, wn = (w & 1) * 64;
    int q4 = lane >> 4, li = lane & 15;

    // staging geometry: pass p covers rows p*32 + (tid>>3); 8 chunks of 8
    // elems per row, chunk swizzled: physical chunk c holds logical chunk
    // c ^ (row&7). (row&7) == (tid>>3)&7 for every pass (p*32 = 0 mod 8).
    int srow = tid >> 3;                     // 0..31
    int swc = ((tid & 7) ^ (srow & 7)) * 8;  // swizzled global col chunk
    const bf16* Ag = A + (size_t)(bm * 128 + srow) * K + swc;
    const bf16* Bg = Bt + (size_t)(bn * 128 + srow) * K + swc;

    f32x4 acc[4][4];
#pragma unroll
    for (int mt = 0; mt < 4; ++mt)
#pragma unroll
        for (int nt = 0; nt < 4; ++nt) acc[mt][nt] = (f32x4){0.f, 0.f, 0.f, 0.f};

    int axr = (li & 7) * 8;   // reader-side XOR (row&7)*8, row&7 == li&7

    for (int k0 = 0; k0 < K; k0 += 64) {
        __syncthreads();
#pragma unroll
        for (int p = 0; p < 4; ++p) {
            gload_lds16(Ag + (size_t)(p * 32) * K + k0, As + p * 2048 + tid * 8);
            gload_lds16(Bg + (size_t)(p * 32) * K + k0, Bs + p * 2048 + tid * 8);
        }
        __syncthreads();
#pragma unroll
        for (int kk = 0; kk < 2; ++kk) {
            int lc = kk * 32 + q4 * 8;        // logical col offset (elems)
            int sc2 = lc ^ axr;               // swizzled col offset
            short8 af[4], bfb[4];
#pragma unroll
            for (int mt = 0; mt < 4; ++mt)
                af[mt] = *(const short8*)(As + (wm + mt * 16 + li) * 64 + sc2);
#pragma unroll
            for (int nt = 0; nt < 4; ++nt)
                bfb[nt] = *(const short8*)(Bs + (wn + nt * 16 + li) * 64 + sc2);
#pragma unroll
            for (int mt = 0; mt < 4; ++mt)
#pragma unroll
                for (int nt = 0; nt < 4; ++nt)
                    acc[mt][nt] = MFMA16(af[mt], bfb[nt], acc[mt][nt]);
        }
    }

    int rowb = bm * 128 + wm;
    if (bn < 16) {
        // Q pre-scale: s1 = 0.125 * log2(e); K columns unscaled.
        float qs = (bn < 8) ? 0.1803368801111204f : 1.0f;
#pragma unroll
        for (int mt = 0; mt < 4; ++mt) {
#pragma unroll
            for (int nt = 0; nt < 4; ++nt) {
                int col = bn * 128 + wn + nt * 16 + li;
#pragma unroll
                for (int r = 0; r < 4; ++r) {
                    int row = rowb + mt * 16 + q4 * 4 + r;
                    QK[(size_t)row * 2048 + col] = __float2bfloat16(acc[mt][nt][r] * qs);
                }
            }
        }
    } else {
#pragma unroll
        for (int mt = 0; mt < 4; ++mt) {
            int sbase = rowb + mt * 16 + q4 * 4;
            int b = sbase >> 11, s = sbase & 2047;
#pragma unroll
            for (int nt = 0; nt < 4; ++nt) {
                int n = bn * 128 + wn + nt * 16 + li - 2048;
                int h = n >> 6, d = n & 63;
                union { bf16 h4[4]; uint2 u; } pk;
#pragma unroll
                for (int r = 0; r < 4; ++r) pk.h4[r] = __float2bfloat16(acc[mt][nt][r]);
                *(uint2*)(Vt + (size_t)((b * 16 + h) * 64 + d) * 2048 + s) = pk.u;
            }
        }
    }
}

// ---------------------------------------------------------------------------
// Kernel 4: flash attention — EXACT round-1 structure (frozen; six rewrites
//  refuted). Q pre-scaled by s1 in gemm_qkv (round-14 win). Staging,
//  barriers, LDS layout, schedule: DO NOT PERTURB.
// ---------------------------------------------------------------------------
__global__ __launch_bounds__(256, 3) void attn_kernel(
    const bf16* __restrict__ QK, const bf16* __restrict__ Vt,
    const float* __restrict__ x, const float* __restrict__ gch,
    bf16* __restrict__ AO) {
    const int S = 2048;
    // LPT schedule: h=0 blocks (32 tiles) first, then causal descending ti.
    int idx = blockIdx.x;
    int ti, h, b;
    if (idx < 64) { h = 0; b = idx & 1; ti = idx >> 1; }
    else {
        int i2 = idx - 64;
        int row = i2 / 30;
        int j = i2 - row * 30;
        ti = 31 - row; h = 1 + (j >> 1); b = j & 1;
    }
    int i0 = ti * 64;
    int tid = threadIdx.x, lane = tid & 63, w = tid >> 6;
    int q4 = lane >> 4, li = lane & 15;

    // 36864 B union:
    //   loop phase:    KsB[2][64*72] (0..18432) | VsB[2][64*72] (18432..36864)
    //   epilogue:      Ored[64*68] f32 (0..17408) | lsumBuf[4][64] (17408..18432)
    __shared__ __align__(16) char smem[36864];
    bf16* KsB = (bf16*)smem;
    bf16* VsB = (bf16*)(smem + 18432);
    float* Ored = (float*)smem;
    float* lsumBuf = (float*)(smem + 17408);

    // each wave holds ALL 64 q rows (B-operand frags for S^T)
    short8 qf[4][2];
#pragma unroll
    for (int it = 0; it < 4; ++it) {
        const bf16* qp = QK + (size_t)(b * S + i0 + it * 16 + li) * 2048 + h * 64 + q4 * 8;
        qf[it][0] = *(const short8*)(qp);
        qf[it][1] = *(const short8*)(qp + 32);
    }

    const float L2E = 1.4426950408889634f;
    float slope = exp2f(-0.5f * (float)(h + 1));
    float sl1 = slope * L2E;           // coeff of (j - i)
    const float slope0_1 = 0.70710678118654752f * L2E;

    float tgt[4]; int gcm[4];
    if (h == 0) {
#pragma unroll
        for (int it = 0; it < 4; ++it) {
            size_t ix = (size_t)(b * S + i0 + it * 16 + li);
            gcm[it] = gch[ix] > 0.5f ? 1 : 0;
            tgt[it] = x[ix * 1024 + 1008] + 1.0f + x[ix * 1024 + 1009];
        }
    } else {
#pragma unroll
        for (int it = 0; it < 4; ++it) { gcm[it] = 0; tgt[it] = 0.f; }
    }

    float lsum[4] = {0.f, 0.f, 0.f, 0.f};
    f32x4 o[4][4];                     // [it][dt] partial O over wave's j-slice
#pragma unroll
    for (int it = 0; it < 4; ++it)
#pragma unroll
        for (int dt = 0; dt < 4; ++dt) o[it][dt] = (f32x4){0.f, 0.f, 0.f, 0.f};

    int srow = tid >> 3, scv = (tid & 7) * 8;
    const bf16* Kg = QK + (size_t)(b * S + srow) * 2048 + 1024 + h * 64 + scv;
    const bf16* Vg = Vt + (size_t)((b * 16 + h) * 64 + srow) * 2048 + scv;

    int ntiles = (h == 0) ? (S / 64) : (ti + 1);

    // prologue: stage tile 0 into buf 0
    {
        uint4 kv0 = *(const uint4*)(Kg);
        uint4 kv1 = *(const uint4*)(Kg + (size_t)32 * 2048);
        uint4 vv0 = *(const uint4*)(Vg);
        uint4 vv1 = *(const uint4*)(Vg + (size_t)32 * 2048);
        *(uint4*)(KsB + srow * 72 + scv) = kv0;
        *(uint4*)(KsB + (srow + 32) * 72 + scv) = kv1;
        *(uint4*)(VsB + srow * 72 + scv) = vv0;
        *(uint4*)(VsB + (srow + 32) * 72 + scv) = vv1;
    }
    __syncthreads();

    int cur = 0;
    for (int jt = 0; jt < ntiles; ++jt) {
        int j0 = jt * 64;
        // issue next-tile loads EARLY (latency hides under compute below)
        uint4 nk0, nk1, nv0, nv1;
        bool pref = (jt + 1 < ntiles);
        if (pref) {
            int jn = j0 + 64;
            nk0 = *(const uint4*)(Kg + (size_t)jn * 2048);
            nk1 = *(const uint4*)(Kg + (size_t)(jn + 32) * 2048);
            nv0 = *(const uint4*)(Vg + jn);
            nv1 = *(const uint4*)(Vg + (size_t)32 * 2048 + jn);
        }
        const bf16* Ks = KsB + cur * 4608;
        const bf16* Vs = VsB + cur * 4608;

        // S^T for wave's j-slice (rows j = j0 + w*16 + q4*4 + r, cols i = li)
        short8 kf0 = *(const short8*)(Ks + (w * 16 + li) * 72 + q4 * 8);
        short8 kf1 = *(const short8*)(Ks + (w * 16 + li) * 72 + 32 + q4 * 8);
        f32x4 sAcc[4];
#pragma unroll
        for (int it = 0; it < 4; ++it) {
            f32x4 z = (f32x4){0.f, 0.f, 0.f, 0.f};
            z = MFMA16(kf0, qf[it][0], z);
            z = MFMA16(kf1, qf[it][1], z);
            sAcc[it] = z;
        }

        float jbase = (float)(j0 + w * 16 + q4 * 4);
        int maskable = (jt >= ti);
        short4v pf[4];
#pragma unroll
        for (int it = 0; it < 4; ++it) {
            float fi = (float)(i0 + it * 16 + li);
            float d0 = jbase - fi;
            union { bf16 hh[4]; short4v v; } pu;
#pragma unroll
            for (int r = 0; r < 4; ++r) {
                float dj = d0 + (float)r;
                float s = fmaf(sl1, dj, sAcc[it][r]);   // Q pre-scaled by s1
                float p;
                if (h == 0) {
                    float jj = jbase + (float)r;
                    float sg = -slope0_1 * fabsf(tgt[it] - jj);
                    s = gcm[it] ? sg : s;
                    bool msk = (!gcm[it]) && (dj > 0.f);
                    p = msk ? 0.f : exp2f(s);
                } else {
                    p = exp2f(s);
                    if (maskable && dj > 0.f) p = 0.f;
                }
                lsum[it] += p;
                pu.hh[r] = __float2bfloat16(p);
            }
            pf[it] = pu.v;
        }

        // PV: o[it][dt] += P_slice · V_slice  (16x16x16, A-frag = pf in-regs)
#pragma unroll
        for (int dt = 0; dt < 4; ++dt) {
            short4v vf = *(const short4v*)(Vs + (dt * 16 + li) * 72 + w * 16 + q4 * 4);
#pragma unroll
            for (int it = 0; it < 4; ++it)
                o[it][dt] = MFMA_PV(pf[it], vf, o[it][dt]);
        }

        // land prefetch into the other buffer (safe: buf[cur^1] reads all
        // completed before the barrier at the end of the previous iteration)
        if (pref) {
            bf16* Kn = KsB + (cur ^ 1) * 4608;
            bf16* Vn = VsB + (cur ^ 1) * 4608;
            *(uint4*)(Kn + srow * 72 + scv) = nk0;
            *(uint4*)(Kn + (srow + 32) * 72 + scv) = nk1;
            *(uint4*)(Vn + srow * 72 + scv) = nv0;
            *(uint4*)(Vn + (srow + 32) * 72 + scv) = nv1;
        }
        __syncthreads();
        cur ^= 1;
    }

    // finalize lsum (reduce over q4 groups; each lane covers i = it*16+li)
#pragma unroll
    for (int it = 0; it < 4; ++it) {
        lsum[it] += __shfl_xor(lsum[it], 16, 64);
        lsum[it] += __shfl_xor(lsum[it], 32, 64);
    }
    if (lane < 16) {
#pragma unroll
        for (int it = 0; it < 4; ++it) lsumBuf[w * 64 + it * 16 + lane] = lsum[it];
    }

    // cross-wave O reduction (serial rounds; o rows are i-local = q4*4+r)
    __syncthreads();
    if (w == 0) {
#pragma unroll
        for (int it = 0; it < 4; ++it)
#pragma unroll
            for (int dt = 0; dt < 4; ++dt)
#pragma unroll
                for (int r = 0; r < 4; ++r)
                    Ored[(it * 16 + q4 * 4 + r) * 68 + dt * 16 + li] = o[it][dt][r];
    }
    __syncthreads();
    if (w == 1) {
#pragma unroll
        for (int it = 0; it < 4; ++it)
#pragma unroll
            for (int dt = 0; dt < 4; ++dt)
#pragma unroll
                for (int r = 0; r < 4; ++r)
                    Ored[(it * 16 + q4 * 4 + r) * 68 + dt * 16 + li] += o[it][dt][r];
    }
    __syncthreads();
    if (w == 2) {
#pragma unroll
        for (int it = 0; it < 4; ++it)
#pragma unroll
            for (int dt = 0; dt < 4; ++dt)
#pragma unroll
                for (int r = 0; r < 4; ++r)
                    Ored[(it * 16 + q4 * 4 + r) * 68 + dt * 16 + li] += o[it][dt][r];
    }
    __syncthreads();
    if (w == 3) {
#pragma unroll
        for (int it = 0; it < 4; ++it)
#pragma unroll
            for (int dt = 0; dt < 4; ++dt)
#pragma unroll
                for (int r = 0; r < 4; ++r)
                    Ored[(it * 16 + q4 * 4 + r) * 68 + dt * 16 + li] += o[it][dt][r];
    }
    __syncthreads();

    // epilogue: thread t -> row i = t>>2, 16-wide d segment
    int i = tid >> 2, dseg = (tid & 3) * 16;
    float ls = lsumBuf[0 * 64 + i] + lsumBuf[1 * 64 + i] + lsumBuf[2 * 64 + i] + lsumBuf[3 * 64 + i];
    float inv = 1.0f / ls;
    bf16* dst = AO + (size_t)(b * S + i0 + i) * 1024 + h * 64 + dseg;
    union { bf16 hh[16]; uint4 u[2]; } ou;
#pragma unroll
    for (int c = 0; c < 16; ++c)
        ou.hh[c] = __float2bfloat16(Ored[i * 68 + dseg + c] * inv);
    *(uint4*)(dst) = ou.u[0];
    *(uint4*)(dst + 8) = ou.u[1];
}

// ---------------------------------------------------------------------------
// Kernel 5: GEMM2  out = x + AO @ WoT^T (fp32 out) — 64x128 tile, 512 blocks
// (round-12 win) + fused io_fix epilogue (round-13 win).
// ---------------------------------------------------------------------------
__global__ __launch_bounds__(256) void gemm_out_kernel(
    const bf16* __restrict__ A, const bf16* __restrict__ Bt,
    const float* __restrict__ x, float* __restrict__ out,
    const float* __restrict__ gch, const float* __restrict__ pch) {
    const int K = 1024;
    int bm = blockIdx.x, bn = blockIdx.y;
    __shared__ bf16 As[64 * 32];
    __shared__ bf16 Bs[128 * 32];
    int tid = threadIdx.x;
    int lane = tid & 63, w = tid >> 6;
    int wm = (w >> 1) * 32, wn = (w & 1) * 64;
    int q4 = lane >> 4, li = lane & 15;
    int srow = tid >> 2, sc = (tid & 3) * 8;

    const bf16* Ag = A + (size_t)(bm * 64 + srow) * K + sc;
    const bf16* Bg = Bt + (size_t)(bn * 128 + srow) * K + sc;
    bf16* Asl = As + tid * 8;            // A: 64x32 = one 256-thread pass
    bf16* Bsl = Bs + tid * 8;            // B rows 0..63
    bf16* Bsl2 = Bs + 2048 + tid * 8;    // B rows 64..127

    f32x4 acc[2][4];
#pragma unroll
    for (int mt = 0; mt < 2; ++mt)
#pragma unroll
        for (int nt = 0; nt < 4; ++nt) acc[mt][nt] = (f32x4){0.f, 0.f, 0.f, 0.f};

    for (int k0 = 0; k0 < K; k0 += 32) {
        __syncthreads();
        gload_lds16(Ag + k0, Asl);
        gload_lds16(Bg + k0, Bsl);
        gload_lds16(Bg + 64 * K + k0, Bsl2);
        __syncthreads();
        short8 af[2], bfb[4];
#pragma unroll
        for (int mt = 0; mt < 2; ++mt)
            af[mt] = *(const short8*)(As + (wm + mt * 16 + li) * 32 + q4 * 8);
#pragma unroll
        for (int nt = 0; nt < 4; ++nt)
            bfb[nt] = *(const short8*)(Bs + (wn + nt * 16 + li) * 32 + q4 * 8);
#pragma unroll
        for (int mt = 0; mt < 2; ++mt)
#pragma unroll
            for (int nt = 0; nt < 4; ++nt)
                acc[mt][nt] = MFMA16(af[mt], bfb[nt], acc[mt][nt]);
    }

#pragma unroll
    for (int mt = 0; mt < 2; ++mt) {
#pragma unroll
        for (int nt = 0; nt < 4; ++nt) {
            int col = bn * 128 + wn + nt * 16 + li;
#pragma unroll
            for (int r = 0; r < 4; ++r) {
                int row = bm * 64 + wm + mt * 16 + q4 * 4 + r;
                size_t idx = (size_t)row * 1024 + col;
                float v = x[idx] + acc[mt][nt][r];
                if (col == 1009) v += gch[row];          // read_offset += getchar
                else if (col == 1011) v += pch[row];     // write_offset += putchar
                else if (col == 1021) v = pch[row];      // output_ready = putchar
                out[idx] = v;
            }
        }
    }
}

// ---------------------------------------------------------------------------
extern "C" void kernel_launch(void* const* d_in, const int* in_sizes, int n_in,
                              void* d_out, int out_size, void* d_ws, size_t ws_size,
                              hipStream_t stream) {
    (void)in_sizes; (void)n_in; (void)out_size; (void)ws_size;
    const float* x   = (const float*)d_in[0];
    const float* gch = (const float*)d_in[1];
    const float* pch = (const float*)d_in[2];
    const float* wq  = (const float*)d_in[3];
    const float* wk  = (const float*)d_in[4];
    const float* wv  = (const float*)d_in[5];
    const float* wo  = (const float*)d_in[6];
    float* out = (float*)d_out;

    char* ws = (char*)d_ws;
    bf16* Xb    = (bf16*)(ws);
    bf16* WqkvT = (bf16*)(ws + (size_t)( 8 << 20));
    bf16* WoT   = (bf16*)(ws + (size_t)(14 << 20));
    bf16* QK    = (bf16*)(ws + (size_t)(16 << 20));
    bf16* Vt    = (bf16*)(ws + (size_t)(32 << 20));
    bf16* AO    = Xb;  // Xb dead after gemm_qkv

    prep_kernel<<<5120, 256, 0, stream>>>(x, Xb, wq, wk, wv, wo, WqkvT, WoT);
    gemm_qkv_kernel<<<dim3(32, 24), 256, 0, stream>>>(Xb, WqkvT, QK, Vt);
    attn_kernel<<<1024, 256, 0, stream>>>(QK, Vt, x, gch, AO);
    gemm_out_kernel<<<dim3(64, 8), 256, 0, stream>>>(AO, WoT, x, out, gch, pch);
}

// Round 18
// 199.232 us; speedup vs baseline: 1.0268x; 1.0268x over previous
//
#include <hip/hip_runtime.h>
#include <hip/hip_bf16.h>

typedef __hip_bfloat16 bf16;
typedef __attribute__((ext_vector_type(8))) short short8;   // 8 bf16 = 4 VGPRs (x32 A/B frag)
typedef __attribute__((ext_vector_type(4))) short short4v;  // 4 bf16 = 2 VGPRs (x16 A/B frag)
typedef __attribute__((ext_vector_type(4))) float f32x4;    // MFMA C/D frag

#define MFMA16(a, b, c) __builtin_amdgcn_mfma_f32_16x16x32_bf16((a), (b), (c), 0, 0, 0)

// 16x16x16 bf16 MFMA: builtin name varies across ROCm; asm fallback.
#if __has_builtin(__builtin_amdgcn_mfma_f32_16x16x16bf16_1k)
#define MFMA_PV(a, b, c) __builtin_amdgcn_mfma_f32_16x16x16bf16_1k((a), (b), (c), 0, 0, 0)
#elif __has_builtin(__builtin_amdgcn_mfma_f32_16x16x16_bf16)
#define MFMA_PV(a, b, c) __builtin_amdgcn_mfma_f32_16x16x16_bf16((a), (b), (c), 0, 0, 0)
#else
static __device__ __forceinline__ f32x4 mfma_pv_asm(short4v a, short4v b, f32x4 c) {
    f32x4 d;
    asm volatile("v_mfma_f32_16x16x16_bf16 %0, %1, %2, %3"
                 : "=&v"(d) : "v"(a), "v"(b), "v"(c));
    return d;
}
#define MFMA_PV(a, b, c) mfma_pv_asm((a), (b), (c))
#endif

// async global->LDS, 16B per lane; LDS dest must be wave-uniform base + lane*16
static __device__ __forceinline__ void gload_lds16(const bf16* g, bf16* l) {
    __builtin_amdgcn_global_load_lds((const __attribute__((address_space(1))) void*)g,
                                     (__attribute__((address_space(3))) void*)l, 16, 0, 0);
}

// ---------------------------------------------------------------------------
// Kernel 1 (merged): preprocessing — blocks 0..1023 transpose+cast weights,
// blocks 1024..5119 cast x (fp32->bf16). One launch (round-11 win, ~2.5 us).
// ---------------------------------------------------------------------------
__global__ __launch_bounds__(256) void prep_kernel(
    const float* __restrict__ x, bf16* __restrict__ Xb,
    const float* __restrict__ wq, const float* __restrict__ wk,
    const float* __restrict__ wv, const float* __restrict__ wo,
    bf16* __restrict__ WqkvT, bf16* __restrict__ WoT) {
    __shared__ bf16 tile[64][65];
    int bidx = blockIdx.x;
    if (bidx >= 1024) {
        // cast path
        int i = ((bidx - 1024) * 256 + threadIdx.x) * 4;
        float4 v = *(const float4*)(x + i);
        union { bf16 h4[4]; uint2 u; } p;
        p.h4[0] = __float2bfloat16(v.x);
        p.h4[1] = __float2bfloat16(v.y);
        p.h4[2] = __float2bfloat16(v.z);
        p.h4[3] = __float2bfloat16(v.w);
        *(uint2*)(Xb + i) = p.u;
        return;
    }
    // transpose path
    int mat = bidx >> 8;
    int t   = bidx & 255;
    int tn  = t >> 4, tk = t & 15;
    const float* src = (mat == 0) ? wq : (mat == 1) ? wk : (mat == 2) ? wv : wo;
    bf16* dst = (mat < 3) ? (WqkvT + (size_t)mat * 1024 * 1024) : WoT;
    int tx = threadIdx.x & 63, ty = threadIdx.x >> 6;
    int k0 = tk * 64, n0 = tn * 64;
#pragma unroll
    for (int p = 0; p < 16; ++p) {
        int r = p * 4 + ty;
        tile[r][tx] = __float2bfloat16(src[(size_t)(k0 + r) * 1024 + n0 + tx]);
    }
    __syncthreads();
#pragma unroll
    for (int p = 0; p < 16; ++p) {
        int r = p * 4 + ty;
        dst[(size_t)(n0 + r) * 1024 + k0 + tx] = tile[tx][r];
    }
}

// ---------------------------------------------------------------------------
// Kernel 3: GEMM1  QKV = Xb @ WqkvT^T — R14-exact m97-style version (best
// measured: 198.19 us total). Round-16's BK=64+swizzle variant regressed
// ~6 us (swizzle addressing VALU on every frag read outweighed halved
// barrier drains) — reverted per falsifier. Q pre-scale by s1 retained.
// ---------------------------------------------------------------------------
__global__ __launch_bounds__(256) void gemm_qkv_kernel(
    const bf16* __restrict__ A, const bf16* __restrict__ Bt,
    bf16* __restrict__ QK, bf16* __restrict__ Vt) {
    const int K = 1024;
    int bm = blockIdx.x, bn = blockIdx.y;
    __shared__ bf16 As[128 * 32];
    __shared__ bf16 Bs[128 * 32];
    int tid = threadIdx.x;
    int lane = tid & 63, w = tid >> 6;
    int wm = (w >> 1) * 64, wn = (w & 1) * 64;
    int q4 = lane >> 4, li = lane & 15;
    int srow = tid >> 2, sc = (tid & 3) * 8;

    const bf16* Ag = A + (size_t)(bm * 128 + srow) * K + sc;
    const bf16* Bg = Bt + (size_t)(bn * 128 + srow) * K + sc;
    bf16* Asl = As + tid * 8;           // row srow, col sc  (lane-contiguous 16B)
    bf16* Asl2 = As + 2048 + tid * 8;   // row srow+64
    bf16* Bsl = Bs + tid * 8;
    bf16* Bsl2 = Bs + 2048 + tid * 8;

    f32x4 acc[4][4];
#pragma unroll
    for (int mt = 0; mt < 4; ++mt)
#pragma unroll
        for (int nt = 0; nt < 4; ++nt) acc[mt][nt] = (f32x4){0.f, 0.f, 0.f, 0.f};

    for (int k0 = 0; k0 < K; k0 += 32) {
        __syncthreads();
        gload_lds16(Ag + k0, Asl);
        gload_lds16(Ag + 64 * K + k0, Asl2);
        gload_lds16(Bg + k0, Bsl);
        gload_lds16(Bg + 64 * K + k0, Bsl2);
        __syncthreads();
        short8 af[4], bfb[4];
#pragma unroll
        for (int mt = 0; mt < 4; ++mt)
            af[mt] = *(const short8*)(As + (wm + mt * 16 + li) * 32 + q4 * 8);
#pragma unroll
        for (int nt = 0; nt < 4; ++nt)
            bfb[nt] = *(const short8*)(Bs + (wn + nt * 16 + li) * 32 + q4 * 8);
#pragma unroll
        for (int mt = 0; mt < 4; ++mt)
#pragma unroll
            for (int nt = 0; nt < 4; ++nt)
                acc[mt][nt] = MFMA16(af[mt], bfb[nt], acc[mt][nt]);
    }

    int rowb = bm * 128 + wm;
    if (bn < 16) {
        // Q pre-scale: s1 = 0.125 * log2(e); K columns unscaled.
        float qs = (bn < 8) ? 0.1803368801111204f : 1.0f;
#pragma unroll
        for (int mt = 0; mt < 4; ++mt) {
#pragma unroll
            for (int nt = 0; nt < 4; ++nt) {
                int col = bn * 128 + wn + nt * 16 + li;
#pragma unroll
                for (int r = 0; r < 4; ++r) {
                    int row = rowb + mt * 16 + q4 * 4 + r;
                    QK[(size_t)row * 2048 + col] = __float2bfloat16(acc[mt][nt][r] * qs);
                }
            }
        }
    } else {
#pragma unroll
        for (int mt = 0; mt < 4; ++mt) {
            int sbase = rowb + mt * 16 + q4 * 4;
            int b = sbase >> 11, s = sbase & 2047;
#pragma unroll
            for (int nt = 0; nt < 4; ++nt) {
                int n = bn * 128 + wn + nt * 16 + li - 2048;
                int h = n >> 6, d = n & 63;
                union { bf16 h4[4]; uint2 u; } pk;
#pragma unroll
                for (int r = 0; r < 4; ++r) pk.h4[r] = __float2bfloat16(acc[mt][nt][r]);
                *(uint2*)(Vt + (size_t)((b * 16 + h) * 64 + d) * 2048 + s) = pk.u;
            }
        }
    }
}

// ---------------------------------------------------------------------------
// Kernel 4: flash attention — EXACT round-1 structure (frozen; seven variants
//  refuted). Q pre-scaled by s1 in gemm_qkv (round-14 win). Staging,
//  barriers, LDS layout, schedule: DO NOT PERTURB.
// ---------------------------------------------------------------------------
__global__ __launch_bounds__(256, 3) void attn_kernel(
    const bf16* __restrict__ QK, const bf16* __restrict__ Vt,
    const float* __restrict__ x, const float* __restrict__ gch,
    bf16* __restrict__ AO) {
    const int S = 2048;
    // LPT schedule: h=0 blocks (32 tiles) first, then causal descending ti.
    int idx = blockIdx.x;
    int ti, h, b;
    if (idx < 64) { h = 0; b = idx & 1; ti = idx >> 1; }
    else {
        int i2 = idx - 64;
        int row = i2 / 30;
        int j = i2 - row * 30;
        ti = 31 - row; h = 1 + (j >> 1); b = j & 1;
    }
    int i0 = ti * 64;
    int tid = threadIdx.x, lane = tid & 63, w = tid >> 6;
    int q4 = lane >> 4, li = lane & 15;

    // 36864 B union:
    //   loop phase:    KsB[2][64*72] (0..18432) | VsB[2][64*72] (18432..36864)
    //   epilogue:      Ored[64*68] f32 (0..17408) | lsumBuf[4][64] (17408..18432)
    __shared__ __align__(16) char smem[36864];
    bf16* KsB = (bf16*)smem;
    bf16* VsB = (bf16*)(smem + 18432);
    float* Ored = (float*)smem;
    float* lsumBuf = (float*)(smem + 17408);

    // each wave holds ALL 64 q rows (B-operand frags for S^T)
    short8 qf[4][2];
#pragma unroll
    for (int it = 0; it < 4; ++it) {
        const bf16* qp = QK + (size_t)(b * S + i0 + it * 16 + li) * 2048 + h * 64 + q4 * 8;
        qf[it][0] = *(const short8*)(qp);
        qf[it][1] = *(const short8*)(qp + 32);
    }

    const float L2E = 1.4426950408889634f;
    float slope = exp2f(-0.5f * (float)(h + 1));
    float sl1 = slope * L2E;           // coeff of (j - i)
    const float slope0_1 = 0.70710678118654752f * L2E;

    float tgt[4]; int gcm[4];
    if (h == 0) {
#pragma unroll
        for (int it = 0; it < 4; ++it) {
            size_t ix = (size_t)(b * S + i0 + it * 16 + li);
            gcm[it] = gch[ix] > 0.5f ? 1 : 0;
            tgt[it] = x[ix * 1024 + 1008] + 1.0f + x[ix * 1024 + 1009];
        }
    } else {
#pragma unroll
        for (int it = 0; it < 4; ++it) { gcm[it] = 0; tgt[it] = 0.f; }
    }

    float lsum[4] = {0.f, 0.f, 0.f, 0.f};
    f32x4 o[4][4];                     // [it][dt] partial O over wave's j-slice
#pragma unroll
    for (int it = 0; it < 4; ++it)
#pragma unroll
        for (int dt = 0; dt < 4; ++dt) o[it][dt] = (f32x4){0.f, 0.f, 0.f, 0.f};

    int srow = tid >> 3, scv = (tid & 7) * 8;
    const bf16* Kg = QK + (size_t)(b * S + srow) * 2048 + 1024 + h * 64 + scv;
    const bf16* Vg = Vt + (size_t)((b * 16 + h) * 64 + srow) * 2048 + scv;

    int ntiles = (h == 0) ? (S / 64) : (ti + 1);

    // prologue: stage tile 0 into buf 0
    {
        uint4 kv0 = *(const uint4*)(Kg);
        uint4 kv1 = *(const uint4*)(Kg + (size_t)32 * 2048);
        uint4 vv0 = *(const uint4*)(Vg);
        uint4 vv1 = *(const uint4*)(Vg + (size_t)32 * 2048);
        *(uint4*)(KsB + srow * 72 + scv) = kv0;
        *(uint4*)(KsB + (srow + 32) * 72 + scv) = kv1;
        *(uint4*)(VsB + srow * 72 + scv) = vv0;
        *(uint4*)(VsB + (srow + 32) * 72 + scv) = vv1;
    }
    __syncthreads();

    int cur = 0;
    for (int jt = 0; jt < ntiles; ++jt) {
        int j0 = jt * 64;
        // issue next-tile loads EARLY (latency hides under compute below)
        uint4 nk0, nk1, nv0, nv1;
        bool pref = (jt + 1 < ntiles);
        if (pref) {
            int jn = j0 + 64;
            nk0 = *(const uint4*)(Kg + (size_t)jn * 2048);
            nk1 = *(const uint4*)(Kg + (size_t)(jn + 32) * 2048);
            nv0 = *(const uint4*)(Vg + jn);
            nv1 = *(const uint4*)(Vg + (size_t)32 * 2048 + jn);
        }
        const bf16* Ks = KsB + cur * 4608;
        const bf16* Vs = VsB + cur * 4608;

        // S^T for wave's j-slice (rows j = j0 + w*16 + q4*4 + r, cols i = li)
        short8 kf0 = *(const short8*)(Ks + (w * 16 + li) * 72 + q4 * 8);
        short8 kf1 = *(const short8*)(Ks + (w * 16 + li) * 72 + 32 + q4 * 8);
        f32x4 sAcc[4];
#pragma unroll
        for (int it = 0; it < 4; ++it) {
            f32x4 z = (f32x4){0.f, 0.f, 0.f, 0.f};
            z = MFMA16(kf0, qf[it][0], z);
            z = MFMA16(kf1, qf[it][1], z);
            sAcc[it] = z;
        }

        float jbase = (float)(j0 + w * 16 + q4 * 4);
        int maskable = (jt >= ti);
        short4v pf[4];
#pragma unroll
        for (int it = 0; it < 4; ++it) {
            float fi = (float)(i0 + it * 16 + li);
            float d0 = jbase - fi;
            union { bf16 hh[4]; short4v v; } pu;
#pragma unroll
            for (int r = 0; r < 4; ++r) {
                float dj = d0 + (float)r;
                float s = fmaf(sl1, dj, sAcc[it][r]);   // Q pre-scaled by s1
                float p;
                if (h == 0) {
                    float jj = jbase + (float)r;
                    float sg = -slope0_1 * fabsf(tgt[it] - jj);
                    s = gcm[it] ? sg : s;
                    bool msk = (!gcm[it]) && (dj > 0.f);
                    p = msk ? 0.f : exp2f(s);
                } else {
                    p = exp2f(s);
                    if (maskable && dj > 0.f) p = 0.f;
                }
                lsum[it] += p;
                pu.hh[r] = __float2bfloat16(p);
            }
            pf[it] = pu.v;
        }

        // PV: o[it][dt] += P_slice · V_slice  (16x16x16, A-frag = pf in-regs)
#pragma unroll
        for (int dt = 0; dt < 4; ++dt) {
            short4v vf = *(const short4v*)(Vs + (dt * 16 + li) * 72 + w * 16 + q4 * 4);
#pragma unroll
            for (int it = 0; it < 4; ++it)
                o[it][dt] = MFMA_PV(pf[it], vf, o[it][dt]);
        }

        // land prefetch into the other buffer (safe: buf[cur^1] reads all
        // completed before the barrier at the end of the previous iteration)
        if (pref) {
            bf16* Kn = KsB + (cur ^ 1) * 4608;
            bf16* Vn = VsB + (cur ^ 1) * 4608;
            *(uint4*)(Kn + srow * 72 + scv) = nk0;
            *(uint4*)(Kn + (srow + 32) * 72 + scv) = nk1;
            *(uint4*)(Vn + srow * 72 + scv) = nv0;
            *(uint4*)(Vn + (srow + 32) * 72 + scv) = nv1;
        }
        __syncthreads();
        cur ^= 1;
    }

    // finalize lsum (reduce over q4 groups; each lane covers i = it*16+li)
#pragma unroll
    for (int it = 0; it < 4; ++it) {
        lsum[it] += __shfl_xor(lsum[it], 16, 64);
        lsum[it] += __shfl_xor(lsum[it], 32, 64);
    }
    if (lane < 16) {
#pragma unroll
        for (int it = 0; it < 4; ++it) lsumBuf[w * 64 + it * 16 + lane] = lsum[it];
    }

    // cross-wave O reduction (serial rounds; o rows are i-local = q4*4+r)
    __syncthreads();
    if (w == 0) {
#pragma unroll
        for (int it = 0; it < 4; ++it)
#pragma unroll
            for (int dt = 0; dt < 4; ++dt)
#pragma unroll
                for (int r = 0; r < 4; ++r)
                    Ored[(it * 16 + q4 * 4 + r) * 68 + dt * 16 + li] = o[it][dt][r];
    }
    __syncthreads();
    if (w == 1) {
#pragma unroll
        for (int it = 0; it < 4; ++it)
#pragma unroll
            for (int dt = 0; dt < 4; ++dt)
#pragma unroll
                for (int r = 0; r < 4; ++r)
                    Ored[(it * 16 + q4 * 4 + r) * 68 + dt * 16 + li] += o[it][dt][r];
    }
    __syncthreads();
    if (w == 2) {
#pragma unroll
        for (int it = 0; it < 4; ++it)
#pragma unroll
            for (int dt = 0; dt < 4; ++dt)
#pragma unroll
                for (int r = 0; r < 4; ++r)
                    Ored[(it * 16 + q4 * 4 + r) * 68 + dt * 16 + li] += o[it][dt][r];
    }
    __syncthreads();
    if (w == 3) {
#pragma unroll
        for (int it = 0; it < 4; ++it)
#pragma unroll
            for (int dt = 0; dt < 4; ++dt)
#pragma unroll
                for (int r = 0; r < 4; ++r)
                    Ored[(it * 16 + q4 * 4 + r) * 68 + dt * 16 + li] += o[it][dt][r];
    }
    __syncthreads();

    // epilogue: thread t -> row i = t>>2, 16-wide d segment
    int i = tid >> 2, dseg = (tid & 3) * 16;
    float ls = lsumBuf[0 * 64 + i] + lsumBuf[1 * 64 + i] + lsumBuf[2 * 64 + i] + lsumBuf[3 * 64 + i];
    float inv = 1.0f / ls;
    bf16* dst = AO + (size_t)(b * S + i0 + i) * 1024 + h * 64 + dseg;
    union { bf16 hh[16]; uint4 u[2]; } ou;
#pragma unroll
    for (int c = 0; c < 16; ++c)
        ou.hh[c] = __float2bfloat16(Ored[i * 68 + dseg + c] * inv);
    *(uint4*)(dst) = ou.u[0];
    *(uint4*)(dst + 8) = ou.u[1];
}

// ---------------------------------------------------------------------------
// Kernel 5: GEMM2  out = x + AO @ WoT^T (fp32 out) — 64x128 tile, 512 blocks
// (round-12 win) + fused io_fix epilogue (round-13 win).
// ---------------------------------------------------------------------------
__global__ __launch_bounds__(256) void gemm_out_kernel(
    const bf16* __restrict__ A, const bf16* __restrict__ Bt,
    const float* __restrict__ x, float* __restrict__ out,
    const float* __restrict__ gch, const float* __restrict__ pch) {
    const int K = 1024;
    int bm = blockIdx.x, bn = blockIdx.y;
    __shared__ bf16 As[64 * 32];
    __shared__ bf16 Bs[128 * 32];
    int tid = threadIdx.x;
    int lane = tid & 63, w = tid >> 6;
    int wm = (w >> 1) * 32, wn = (w & 1) * 64;
    int q4 = lane >> 4, li = lane & 15;
    int srow = tid >> 2, sc = (tid & 3) * 8;

    const bf16* Ag = A + (size_t)(bm * 64 + srow) * K + sc;
    const bf16* Bg = Bt + (size_t)(bn * 128 + srow) * K + sc;
    bf16* Asl = As + tid * 8;            // A: 64x32 = one 256-thread pass
    bf16* Bsl = Bs + tid * 8;            // B rows 0..63
    bf16* Bsl2 = Bs + 2048 + tid * 8;    // B rows 64..127

    f32x4 acc[2][4];
#pragma unroll
    for (int mt = 0; mt < 2; ++mt)
#pragma unroll
        for (int nt = 0; nt < 4; ++nt) acc[mt][nt] = (f32x4){0.f, 0.f, 0.f, 0.f};

    for (int k0 = 0; k0 < K; k0 += 32) {
        __syncthreads();
        gload_lds16(Ag + k0, Asl);
        gload_lds16(Bg + k0, Bsl);
        gload_lds16(Bg + 64 * K + k0, Bsl2);
        __syncthreads();
        short8 af[2], bfb[4];
#pragma unroll
        for (int mt = 0; mt < 2; ++mt)
            af[mt] = *(const short8*)(As + (wm + mt * 16 + li) * 32 + q4 * 8);
#pragma unroll
        for (int nt = 0; nt < 4; ++nt)
            bfb[nt] = *(const short8*)(Bs + (wn + nt * 16 + li) * 32 + q4 * 8);
#pragma unroll
        for (int mt = 0; mt < 2; ++mt)
#pragma unroll
            for (int nt = 0; nt < 4; ++nt)
                acc[mt][nt] = MFMA16(af[mt], bfb[nt], acc[mt][nt]);
    }

#pragma unroll
    for (int mt = 0; mt < 2; ++mt) {
#pragma unroll
        for (int nt = 0; nt < 4; ++nt) {
            int col = bn * 128 + wn + nt * 16 + li;
#pragma unroll
            for (int r = 0; r < 4; ++r) {
                int row = bm * 64 + wm + mt * 16 + q4 * 4 + r;
                size_t idx = (size_t)row * 1024 + col;
                float v = x[idx] + acc[mt][nt][r];
                if (col == 1009) v += gch[row];          // read_offset += getchar
                else if (col == 1011) v += pch[row];     // write_offset += putchar
                else if (col == 1021) v = pch[row];      // output_ready = putchar
                out[idx] = v;
            }
        }
    }
}

// ---------------------------------------------------------------------------
extern "C" void kernel_launch(void* const* d_in, const int* in_sizes, int n_in,
                              void* d_out, int out_size, void* d_ws, size_t ws_size,
                              hipStream_t stream) {
    (void)in_sizes; (void)n_in; (void)out_size; (void)ws_size;
    const float* x   = (const float*)d_in[0];
    const float* gch = (const float*)d_in[1];
    const float* pch = (const float*)d_in[2];
    const float* wq  = (const float*)d_in[3];
    const float* wk  = (const float*)d_in[4];
    const float* wv  = (const float*)d_in[5];
    const float* wo  = (const float*)d_in[6];
    float* out = (float*)d_out;

    char* ws = (char*)d_ws;
    bf16* Xb    = (bf16*)(ws);
    bf16* WqkvT = (bf16*)(ws + (size_t)( 8 << 20));
    bf16* WoT   = (bf16*)(ws + (size_t)(14 << 20));
    bf16* QK    = (bf16*)(ws + (size_t)(16 << 20));
    bf16* Vt    = (bf16*)(ws + (size_t)(32 << 20));
    bf16* AO    = Xb;  // Xb dead after gemm_qkv

    prep_kernel<<<5120, 256, 0, stream>>>(x, Xb, wq, wk, wv, wo, WqkvT, WoT);
    gemm_qkv_kernel<<<dim3(32, 24), 256, 0, stream>>>(Xb, WqkvT, QK, Vt);
    attn_kernel<<<1024, 256, 0, stream>>>(QK, Vt, x, gch, AO);
    gemm_out_kernel<<<dim3(64, 8), 256, 0, stream>>>(AO, WoT, x, out, gch, pch);
}